// Round 2
// baseline (530.569 us; speedup 1.0000x reference)
//
#include <hip/hip_runtime.h>

// ---------------------------------------------------------------------------
// ServiceGNN: 2-layer single-head GAT (+self-loops, segment softmax) + FC head
// N=50000, E=800000 (+N self loops), D_in=D_h=128, D_out=57, fp32 throughout.
// Pipeline per call:
//   memset deg -> probe(int64?) -> count -> scan(wave-shfl) -> scatter (CSR by dst)
//   gemm(x,W1)+alphas -> agg(softmax+gather, +b1,relu)
//   gemm(h,W2)+alphas -> agg(+b2)
//   fc head
// ---------------------------------------------------------------------------

#define NEG_SLOPE 0.2f

// ---------------- int64-vs-int32 edge_index probe ----------------
// Reference declares edge_index as int64. If the harness hands us int64, the
// int32 view is [lo,hi,lo,hi,...] with hi==0 (ids < 2^31). If int32, the odd
// words are random src ids — P(first 256 all zero) ~ 0. One wave decides.
__global__ void probe_i64_kernel(const int* __restrict__ ei, int E, int* __restrict__ flag)
{
    int lane = threadIdx.x;              // blockDim = 64
    int v = 0;
    int lim = (E < 256) ? E : 256;
    for (int t = lane; t < lim; t += 64) v |= ei[2 * t + 1];
    #pragma unroll
    for (int o = 32; o >= 1; o >>= 1) v |= __shfl_xor(v, o);
    if (lane == 0) flag[0] = (v == 0) ? 1 : 0;
}

// ---------------- CSR build ----------------

__global__ __launch_bounds__(256) void count_deg_kernel(
    const int* __restrict__ ei, int E, int n,
    const int* __restrict__ flag, int* __restrict__ deg)
{
    int is64 = flag[0];                  // uniform scalar branch
    int i = blockIdx.x * blockDim.x + threadIdx.x;
    if (i >= E + n) return;
    int d;
    if (i < E) d = is64 ? ei[2 * (E + i)] : ei[E + i];   // ei[1][e] = dst
    else       d = i - E;                                 // self loop
    atomicAdd(&deg[d], 1);
}

// Single-block scan, wave-shuffle based: 4 barriers per 1024-chunk.
__global__ __launch_bounds__(1024) void scan_kernel(
    const int* __restrict__ deg, int* __restrict__ rowptr, int n)
{
    __shared__ int wsum[16];
    __shared__ int sbase;
    int tid = threadIdx.x;
    int lane = tid & 63, wv = tid >> 6;
    if (tid == 0) { sbase = 0; rowptr[0] = 0; }
    __syncthreads();
    for (int base = 0; base < n; base += 1024) {
        int i = base + tid;
        int v = (i < n) ? deg[i] : 0;
        // wave-64 inclusive scan
        int s = v;
        #pragma unroll
        for (int off = 1; off < 64; off <<= 1) {
            int t = __shfl_up(s, off);
            if (lane >= off) s += t;
        }
        if (lane == 63) wsum[wv] = s;
        __syncthreads();
        if (wv == 0) {                    // scan the 16 wave sums
            int ws = (lane < 16) ? wsum[lane] : 0;
            #pragma unroll
            for (int off = 1; off < 16; off <<= 1) {
                int t = __shfl_up(ws, off);
                if (lane >= off) ws += t;
            }
            if (lane < 16) wsum[lane] = ws;
        }
        __syncthreads();
        int woff = (wv == 0) ? 0 : wsum[wv - 1];
        int incl = sbase + woff + s;      // reads old sbase
        if (i < n) rowptr[i + 1] = incl;
        __syncthreads();                  // all sbase reads + wsum reads done
        if (tid == 1023) sbase = incl;    // chunk running total (OOB lanes added 0)
        __syncthreads();
    }
}

// Fills col[] reversed within each row via atomicSub on deg (order within a
// row is arbitrary for max/sum reductions). Reuses deg as the cursor.
__global__ __launch_bounds__(256) void scatter_kernel(
    const int* __restrict__ ei, int E, int n,
    const int* __restrict__ flag,
    const int* __restrict__ rowptr, int* __restrict__ deg, int* __restrict__ col)
{
    int is64 = flag[0];
    int i = blockIdx.x * blockDim.x + threadIdx.x;
    if (i >= E + n) return;
    int s, d;
    if (i < E) {
        if (is64) { s = ei[2 * i]; d = ei[2 * (E + i)]; }
        else      { s = ei[i];     d = ei[E + i]; }
    } else {
        s = i - E; d = s;
    }
    int pos = atomicSub(&deg[d], 1) - 1;
    col[rowptr[d] + pos] = s;
}

// ---------------- GEMM (M x 128 @ 128 x 128) with fused alpha dots ----------

// block = 256 threads, tile 64 rows x 128 cols, per-thread 4 rows x 8 cols.
// W fully staged in LDS (64KB, 2 blocks/CU). x streamed from global.
__global__ __launch_bounds__(256, 2) void gemm_h_kernel(
    const float* __restrict__ X, const float* __restrict__ W,
    const float* __restrict__ asv, const float* __restrict__ adv,
    float* __restrict__ H, float* __restrict__ As, float* __restrict__ Ad, int n)
{
    __shared__ float Wl[128 * 128];
    int tid = threadIdx.x;
    {
        const float4* W4 = (const float4*)W;
        float4* Wl4w = (float4*)Wl;
        #pragma unroll
        for (int i = 0; i < 16; ++i) Wl4w[tid + i * 256] = W4[tid + i * 256];
    }
    __syncthreads();

    int cg = tid & 15, rg = tid >> 4;
    int c0 = cg * 8;
    int row0 = blockIdx.x * 64 + rg * 4;
    const float4* Wl4 = (const float4*)Wl;

    float acc[4][8];
    #pragma unroll
    for (int i = 0; i < 4; ++i)
        #pragma unroll
        for (int c = 0; c < 8; ++c) acc[i][c] = 0.f;

    for (int k = 0; k < 128; k += 4) {
        float4 xv[4];
        #pragma unroll
        for (int i = 0; i < 4; ++i) {
            int r = row0 + i;
            if (r < n) xv[i] = *(const float4*)(X + (size_t)r * 128 + k);
            else       xv[i] = make_float4(0.f, 0.f, 0.f, 0.f);
        }
        #pragma unroll
        for (int kk = 0; kk < 4; ++kk) {
            float4 w0 = Wl4[((k + kk) * 128 + c0) >> 2];
            float4 w1 = Wl4[((k + kk) * 128 + c0 + 4) >> 2];
            #pragma unroll
            for (int i = 0; i < 4; ++i) {
                float xs = (kk == 0) ? xv[i].x : (kk == 1) ? xv[i].y
                         : (kk == 2) ? xv[i].z : xv[i].w;
                acc[i][0] += xs * w0.x; acc[i][1] += xs * w0.y;
                acc[i][2] += xs * w0.z; acc[i][3] += xs * w0.w;
                acc[i][4] += xs * w1.x; acc[i][5] += xs * w1.y;
                acc[i][6] += xs * w1.z; acc[i][7] += xs * w1.w;
            }
        }
    }

    // fused alpha epilogue: alpha_s[r] = h[r,:] . a_src ; alpha_d likewise
    float4 as0 = *(const float4*)(asv + c0);
    float4 as1 = *(const float4*)(asv + c0 + 4);
    float4 ad0 = *(const float4*)(adv + c0);
    float4 ad1 = *(const float4*)(adv + c0 + 4);

    #pragma unroll
    for (int i = 0; i < 4; ++i) {
        int r = row0 + i;
        float ps = acc[i][0] * as0.x + acc[i][1] * as0.y + acc[i][2] * as0.z + acc[i][3] * as0.w
                 + acc[i][4] * as1.x + acc[i][5] * as1.y + acc[i][6] * as1.z + acc[i][7] * as1.w;
        float pd = acc[i][0] * ad0.x + acc[i][1] * ad0.y + acc[i][2] * ad0.z + acc[i][3] * ad0.w
                 + acc[i][4] * ad1.x + acc[i][5] * ad1.y + acc[i][6] * ad1.z + acc[i][7] * ad1.w;
        #pragma unroll
        for (int mask = 8; mask >= 1; mask >>= 1) {   // reduce across the 16 cgs
            ps += __shfl_xor(ps, mask);
            pd += __shfl_xor(pd, mask);
        }
        if (r < n) {
            *(float4*)(H + (size_t)r * 128 + c0)     = make_float4(acc[i][0], acc[i][1], acc[i][2], acc[i][3]);
            *(float4*)(H + (size_t)r * 128 + c0 + 4) = make_float4(acc[i][4], acc[i][5], acc[i][6], acc[i][7]);
            if (cg == 0) { As[r] = ps; Ad[r] = pd; }
        }
    }
}

// ---------------- GAT aggregation: one wave per dst node ----------------

__global__ __launch_bounds__(256) void gat_agg_kernel(
    const float* __restrict__ H, const float* __restrict__ As, const float* __restrict__ Ad,
    const int* __restrict__ rowptr, const int* __restrict__ col,
    const float* __restrict__ bias, float* __restrict__ Out, int n, int relu)
{
    int wid = (blockIdx.x * blockDim.x + threadIdx.x) >> 6;
    int lane = threadIdx.x & 63;
    if (wid >= n) return;

    int beg = rowptr[wid], end = rowptr[wid + 1];
    int degn = end - beg;
    float adn = Ad[wid];

    // lanes hold the first 64 edges' src ids for the whole kernel
    int c0r = (lane < degn) ? col[beg + lane] : 0;

    // pass A: leaky-relu logits + segment max
    float e0 = -1e30f;
    if (lane < degn) {
        float e = As[c0r] + adn;
        e0 = (e > 0.f) ? e : NEG_SLOPE * e;
    }
    float m = e0;
    for (int j = beg + lane + 64; j < end; j += 64) {
        float e = As[col[j]] + adn;
        e = (e > 0.f) ? e : NEG_SLOPE * e;
        m = fmaxf(m, e);
    }
    #pragma unroll
    for (int o = 32; o >= 1; o >>= 1) m = fmaxf(m, __shfl_xor(m, o));

    // pass B: denominator; keep first-64 exps in a reg for reuse
    float ex0 = (lane < degn) ? __expf(e0 - m) : 0.f;
    float den = ex0;
    for (int j = beg + lane + 64; j < end; j += 64) {
        float e = As[col[j]] + adn;
        e = (e > 0.f) ? e : NEG_SLOPE * e;
        den += __expf(e - m);
    }
    #pragma unroll
    for (int o = 32; o >= 1; o >>= 1) den += __shfl_xor(den, o);
    float inv = 1.f / den;

    // pass C: weighted gather-aggregate; wave cooperates on 128 floats/edge.
    // src id + weight broadcast from the lane that owns edge jj (no reload).
    const float2* H2 = (const float2*)H;
    float accx = 0.f, accy = 0.f;
    for (int j = beg; j < end; ++j) {
        int jj = j - beg;
        int s; float w;
        if (jj < 64) {
            s = __shfl(c0r, jj);
            w = __shfl(ex0, jj);
        } else {
            s = col[j];                    // uniform address -> broadcast load
            float e = As[s] + adn;
            e = (e > 0.f) ? e : NEG_SLOPE * e;
            w = __expf(e - m);
        }
        float2 hv = H2[(size_t)s * 64 + lane]; // 512B coalesced per edge
        accx += w * hv.x;
        accy += w * hv.y;
    }

    float2 b2 = ((const float2*)bias)[lane];
    float ox = accx * inv + b2.x;
    float oy = accy * inv + b2.y;
    if (relu) { ox = fmaxf(ox, 0.f); oy = fmaxf(oy, 0.f); }
    float2 o2; o2.x = ox; o2.y = oy;
    ((float2*)Out)[(size_t)wid * 64 + lane] = o2;
}

// ---------------- FC head: (M x 128) @ (128 x 57) + b ----------------

// block = 256 threads, tile 64 rows x 60 cols (57 padded), per-thread 4x4.
__global__ __launch_bounds__(256, 2) void fc_kernel(
    const float* __restrict__ H, const float* __restrict__ Wf,
    const float* __restrict__ bf, float* __restrict__ Out, int n)
{
    __shared__ float Wl[128 * 60];   // 30 KB; (k*60+c0) -> 2-way bank alias = free
    int tid = threadIdx.x;
    for (int i = tid; i < 128 * 60; i += 256) {
        int k = i / 60, c = i % 60;
        Wl[i] = (c < 57) ? Wf[k * 57 + c] : 0.f;
    }
    __syncthreads();

    int cg = tid & 15, rg = tid >> 4;
    int c0 = cg * 4;
    int row0 = blockIdx.x * 64 + rg * 4;
    const float4* Wl4 = (const float4*)Wl;

    float acc[4][4];
    #pragma unroll
    for (int i = 0; i < 4; ++i)
        #pragma unroll
        for (int c = 0; c < 4; ++c) acc[i][c] = 0.f;

    for (int k = 0; k < 128; k += 4) {
        float4 xv[4];
        #pragma unroll
        for (int i = 0; i < 4; ++i) {
            int r = row0 + i;
            if (r < n) xv[i] = *(const float4*)(H + (size_t)r * 128 + k);
            else       xv[i] = make_float4(0.f, 0.f, 0.f, 0.f);
        }
        #pragma unroll
        for (int kk = 0; kk < 4; ++kk) {
            float4 wv = Wl4[((k + kk) * 60 + c0) >> 2];
            #pragma unroll
            for (int i = 0; i < 4; ++i) {
                float xs = (kk == 0) ? xv[i].x : (kk == 1) ? xv[i].y
                         : (kk == 2) ? xv[i].z : xv[i].w;
                acc[i][0] += xs * wv.x; acc[i][1] += xs * wv.y;
                acc[i][2] += xs * wv.z; acc[i][3] += xs * wv.w;
            }
        }
    }

    #pragma unroll
    for (int i = 0; i < 4; ++i) {
        int r = row0 + i;
        if (r >= n) continue;
        #pragma unroll
        for (int cc = 0; cc < 4; ++cc) {
            int c = c0 + cc;
            if (c < 57) Out[(size_t)r * 57 + c] = acc[i][cc] + bf[c];
        }
    }
}

// ---------------- launch ----------------

extern "C" void kernel_launch(void* const* d_in, const int* in_sizes, int n_in,
                              void* d_out, int out_size, void* d_ws, size_t ws_size,
                              hipStream_t stream)
{
    const float* x   = (const float*)d_in[0];
    const int*   ei  = (const int*)d_in[1];
    const float* W1  = (const float*)d_in[2];
    const float* a1s = (const float*)d_in[3];
    const float* a1d = (const float*)d_in[4];
    const float* b1  = (const float*)d_in[5];
    const float* W2  = (const float*)d_in[6];
    const float* a2s = (const float*)d_in[7];
    const float* a2d = (const float*)d_in[8];
    const float* b2  = (const float*)d_in[9];
    const float* fcw = (const float*)d_in[10];
    const float* fcb = (const float*)d_in[11];
    float* out = (float*)d_out;

    int n = in_sizes[0] / 128;
    int E = in_sizes[1] / 2;     // element count of edge_index is 2E either dtype
    int tot = E + n;

    char* ws = (char*)d_ws;
    size_t off = 0;
    auto alloc = [&](size_t bytes) -> void* {
        void* p = ws + off;
        off += (bytes + 255) & ~(size_t)255;
        return p;
    };
    float* hA     = (float*)alloc((size_t)n * 128 * 4);
    float* hB     = (float*)alloc((size_t)n * 128 * 4);
    float* As     = (float*)alloc((size_t)n * 4);
    float* Ad     = (float*)alloc((size_t)n * 4);
    int*   rowptr = (int*)alloc((size_t)(n + 1) * 4);
    int*   deg    = (int*)alloc((size_t)n * 4);
    int*   col    = (int*)alloc((size_t)tot * 4);
    int*   flag   = (int*)alloc(256);

    hipMemsetAsync(deg, 0, (size_t)n * 4, stream);

    probe_i64_kernel<<<1, 64, 0, stream>>>(ei, E, flag);

    int nb = (tot + 255) / 256;
    count_deg_kernel<<<nb, 256, 0, stream>>>(ei, E, n, flag, deg);
    scan_kernel<<<1, 1024, 0, stream>>>(deg, rowptr, n);
    scatter_kernel<<<nb, 256, 0, stream>>>(ei, E, n, flag, rowptr, deg, col);

    int gb = (n + 63) / 64;
    int ab = (n + 3) / 4;

    // layer 1
    gemm_h_kernel<<<gb, 256, 0, stream>>>(x, W1, a1s, a1d, hA, As, Ad, n);
    gat_agg_kernel<<<ab, 256, 0, stream>>>(hA, As, Ad, rowptr, col, b1, hB, n, 1);
    // layer 2
    gemm_h_kernel<<<gb, 256, 0, stream>>>(hB, W2, a2s, a2d, hA, As, Ad, n);
    gat_agg_kernel<<<ab, 256, 0, stream>>>(hA, As, Ad, rowptr, col, b2, hB, n, 0);
    // head
    fc_kernel<<<gb, 256, 0, stream>>>(hB, fcw, fcb, out, n);
}

// Round 3
// 384.755 us; speedup vs baseline: 1.3790x; 1.3790x over previous
//
#include <hip/hip_runtime.h>

// ---------------------------------------------------------------------------
// ServiceGNN: 2-layer single-head GAT (+self-loops, segment softmax) + FC head
// N=50000, E=800000 (+N self loops), D_in=D_h=128, D_out=57, fp32 throughout.
// R2: gemm re-tiled (32KB LDS K-split, 32-row blocks, conflict-free W reads),
//     agg gather unrolled x4, scan parallelized (3 kernels), fc re-tiled.
// ---------------------------------------------------------------------------

#define NEG_SLOPE 0.2f

// ---------------- int64-vs-int32 edge_index probe ----------------
__global__ void probe_i64_kernel(const int* __restrict__ ei, int E, int* __restrict__ flag)
{
    int lane = threadIdx.x;              // blockDim = 64
    int v = 0;
    int lim = (E < 256) ? E : 256;
    for (int t = lane; t < lim; t += 64) v |= ei[2 * t + 1];
    #pragma unroll
    for (int o = 32; o >= 1; o >>= 1) v |= __shfl_xor(v, o);
    if (lane == 0) flag[0] = (v == 0) ? 1 : 0;
}

// ---------------- CSR build ----------------

__global__ __launch_bounds__(256) void count_deg_kernel(
    const int* __restrict__ ei, int E, int n,
    const int* __restrict__ flag, int* __restrict__ deg)
{
    int is64 = flag[0];                  // uniform scalar branch
    int i = blockIdx.x * blockDim.x + threadIdx.x;
    if (i >= E + n) return;
    int d;
    if (i < E) d = is64 ? ei[2 * (E + i)] : ei[E + i];   // ei[1][e] = dst
    else       d = i - E;                                 // self loop
    atomicAdd(&deg[d], 1);
}

// scan pass 1: per-1024-chunk inclusive scan (wave shfl), chunk totals out.
__global__ __launch_bounds__(1024) void scan1_kernel(
    const int* __restrict__ deg, int* __restrict__ rowptr,
    int* __restrict__ csum, int n)
{
    __shared__ int wsum[16];
    int b = blockIdx.x, tid = threadIdx.x;
    int lane = tid & 63, wv = tid >> 6;
    int i = b * 1024 + tid;
    int v = (i < n) ? deg[i] : 0;
    int s = v;
    #pragma unroll
    for (int off = 1; off < 64; off <<= 1) {
        int t = __shfl_up(s, off);
        if (lane >= off) s += t;
    }
    if (lane == 63) wsum[wv] = s;
    __syncthreads();
    if (wv == 0) {
        int ws = (lane < 16) ? wsum[lane] : 0;
        #pragma unroll
        for (int off = 1; off < 16; off <<= 1) {
            int t = __shfl_up(ws, off);
            if (lane >= off) ws += t;
        }
        if (lane < 16) wsum[lane] = ws;
    }
    __syncthreads();
    int woff = (wv == 0) ? 0 : wsum[wv - 1];
    int incl = woff + s;                 // chunk-local inclusive scan
    if (i < n) rowptr[i + 1] = incl;
    if (tid == 1023) csum[b] = incl;     // chunk total (OOB lanes added 0)
    if (b == 0 && tid == 0) rowptr[0] = 0;
}

// scan pass 2: one wave scans the <=64 chunk totals (inclusive).
__global__ void scan2_kernel(int* __restrict__ csum, int nb)
{
    int lane = threadIdx.x;              // blockDim = 64
    int v = (lane < nb) ? csum[lane] : 0;
    #pragma unroll
    for (int off = 1; off < 64; off <<= 1) {
        int t = __shfl_up(v, off);
        if (lane >= off) v += t;
    }
    if (lane < nb) csum[lane] = v;
}

// scan pass 3: add chunk base to chunks 1..nb-1.
__global__ __launch_bounds__(1024) void scan3_kernel(
    const int* __restrict__ csum, int* __restrict__ rowptr, int n)
{
    int b = blockIdx.x + 1;
    int i = b * 1024 + threadIdx.x;
    if (i < n) rowptr[i + 1] += csum[b - 1];
}

// Fills col[] reversed within each row via atomicSub on deg (order within a
// row is arbitrary for max/sum reductions). Reuses deg as the cursor.
__global__ __launch_bounds__(256) void scatter_kernel(
    const int* __restrict__ ei, int E, int n,
    const int* __restrict__ flag,
    const int* __restrict__ rowptr, int* __restrict__ deg, int* __restrict__ col)
{
    int is64 = flag[0];
    int i = blockIdx.x * blockDim.x + threadIdx.x;
    if (i >= E + n) return;
    int s, d;
    if (i < E) {
        if (is64) { s = ei[2 * i]; d = ei[2 * (E + i)]; }
        else      { s = ei[i];     d = ei[E + i]; }
    } else {
        s = i - E; d = s;
    }
    int pos = atomicSub(&deg[d], 1) - 1;
    col[rowptr[d] + pos] = s;
}

// ---------------- GEMM (M x 128 @ 128 x 128) with fused alpha dots ----------
// block = 256 threads, tile 32 rows x 128 cols; per-thread 2 rows x 8 cols.
// K split in two 64-k phases so the W stage is 32KB -> 5 blocks/CU.
// Column map c0 = cg*4 / 64+cg*4: 16 lanes read 256 contiguous LDS bytes
// -> f%8 covers all 8 bank groups -> 2-way alias only (free).
__global__ __launch_bounds__(256) void gemm_h_kernel(
    const float* __restrict__ X, const float* __restrict__ W,
    const float* __restrict__ asv, const float* __restrict__ adv,
    float* __restrict__ H, float* __restrict__ As, float* __restrict__ Ad, int n)
{
    __shared__ float Wl[64 * 128];       // 32 KB
    int tid = threadIdx.x;
    int cg = tid & 15, rg = tid >> 4;
    int row0 = blockIdx.x * 32;
    int r0 = row0 + rg * 2, r1 = r0 + 1;
    int rc0 = (r0 < n) ? r0 : (n - 1);   // clamped load rows (branch-free)
    int rc1 = (r1 < n) ? r1 : (n - 1);

    float acc[2][8];
    #pragma unroll
    for (int i = 0; i < 2; ++i)
        #pragma unroll
        for (int c = 0; c < 8; ++c) acc[i][c] = 0.f;

    const float4* Wl4 = (const float4*)Wl;

    #pragma unroll
    for (int p = 0; p < 2; ++p) {
        {   // stage W[p*64 .. p*64+63][:] -> 2048 float4s
            const float4* W4 = (const float4*)(W + p * 64 * 128);
            float4* Wl4w = (float4*)Wl;
            #pragma unroll
            for (int t = 0; t < 8; ++t) Wl4w[tid + t * 256] = W4[tid + t * 256];
        }
        __syncthreads();

        const float* X0 = X + (size_t)rc0 * 128 + p * 64;
        const float* X1 = X + (size_t)rc1 * 128 + p * 64;
        for (int k = 0; k < 64; k += 4) {
            float4 xa = *(const float4*)(X0 + k);
            float4 xb = *(const float4*)(X1 + k);
            #pragma unroll
            for (int kk = 0; kk < 4; ++kk) {
                float4 wA = Wl4[(k + kk) * 32 + cg];
                float4 wB = Wl4[(k + kk) * 32 + 16 + cg];
                float x0s = (kk == 0) ? xa.x : (kk == 1) ? xa.y : (kk == 2) ? xa.z : xa.w;
                float x1s = (kk == 0) ? xb.x : (kk == 1) ? xb.y : (kk == 2) ? xb.z : xb.w;
                acc[0][0] += x0s * wA.x; acc[0][1] += x0s * wA.y;
                acc[0][2] += x0s * wA.z; acc[0][3] += x0s * wA.w;
                acc[0][4] += x0s * wB.x; acc[0][5] += x0s * wB.y;
                acc[0][6] += x0s * wB.z; acc[0][7] += x0s * wB.w;
                acc[1][0] += x1s * wA.x; acc[1][1] += x1s * wA.y;
                acc[1][2] += x1s * wA.z; acc[1][3] += x1s * wA.w;
                acc[1][4] += x1s * wB.x; acc[1][5] += x1s * wB.y;
                acc[1][6] += x1s * wB.z; acc[1][7] += x1s * wB.w;
            }
        }
        __syncthreads();
    }

    // fused alpha epilogue (cols {cg*4..+3} and {64+cg*4..+3})
    float4 asA = *(const float4*)(asv + cg * 4);
    float4 asB = *(const float4*)(asv + 64 + cg * 4);
    float4 adA = *(const float4*)(adv + cg * 4);
    float4 adB = *(const float4*)(adv + 64 + cg * 4);

    #pragma unroll
    for (int i = 0; i < 2; ++i) {
        int r = r0 + i;
        float ps = acc[i][0] * asA.x + acc[i][1] * asA.y + acc[i][2] * asA.z + acc[i][3] * asA.w
                 + acc[i][4] * asB.x + acc[i][5] * asB.y + acc[i][6] * asB.z + acc[i][7] * asB.w;
        float pd = acc[i][0] * adA.x + acc[i][1] * adA.y + acc[i][2] * adA.z + acc[i][3] * adA.w
                 + acc[i][4] * adB.x + acc[i][5] * adB.y + acc[i][6] * adB.z + acc[i][7] * adB.w;
        #pragma unroll
        for (int mask = 8; mask >= 1; mask >>= 1) {   // reduce across the 16 cgs
            ps += __shfl_xor(ps, mask);
            pd += __shfl_xor(pd, mask);
        }
        if (r < n) {
            *(float4*)(H + (size_t)r * 128 + cg * 4)      = make_float4(acc[i][0], acc[i][1], acc[i][2], acc[i][3]);
            *(float4*)(H + (size_t)r * 128 + 64 + cg * 4) = make_float4(acc[i][4], acc[i][5], acc[i][6], acc[i][7]);
            if (cg == 0) { As[r] = ps; Ad[r] = pd; }
        }
    }
}

// ---------------- GAT aggregation: one wave per dst node ----------------

__global__ __launch_bounds__(256) void gat_agg_kernel(
    const float* __restrict__ H, const float* __restrict__ As, const float* __restrict__ Ad,
    const int* __restrict__ rowptr, const int* __restrict__ col,
    const float* __restrict__ bias, float* __restrict__ Out, int n, int relu)
{
    int wid = (blockIdx.x * blockDim.x + threadIdx.x) >> 6;
    int lane = threadIdx.x & 63;
    if (wid >= n) return;

    int beg = rowptr[wid], end = rowptr[wid + 1];
    int degn = end - beg;
    float adn = Ad[wid];

    int c0r = 0;
    if (lane < degn) c0r = col[beg + lane];

    // pass A: leaky-relu logits + segment max
    float e0 = -1e30f;
    if (lane < degn) {
        float e = As[c0r] + adn;
        e0 = (e > 0.f) ? e : NEG_SLOPE * e;
    }
    float m = e0;
    for (int j = beg + lane + 64; j < end; j += 64) {
        float e = As[col[j]] + adn;
        e = (e > 0.f) ? e : NEG_SLOPE * e;
        m = fmaxf(m, e);
    }
    #pragma unroll
    for (int o = 32; o >= 1; o >>= 1) m = fmaxf(m, __shfl_xor(m, o));

    // pass B: denominator; keep first-64 exps in a reg for reuse
    float ex0 = (lane < degn) ? __expf(e0 - m) : 0.f;
    float den = ex0;
    for (int j = beg + lane + 64; j < end; j += 64) {
        float e = As[col[j]] + adn;
        e = (e > 0.f) ? e : NEG_SLOPE * e;
        den += __expf(e - m);
    }
    #pragma unroll
    for (int o = 32; o >= 1; o >>= 1) den += __shfl_xor(den, o);
    float inv = 1.f / den;

    // pass C: weighted gather-aggregate, 4 edges in flight per wave.
    const float2* H2 = (const float2*)H;
    float accx = 0.f, accy = 0.f;
    int nfull = (degn < 64) ? degn : 64;
    int j = 0;
    for (; j + 4 <= nfull; j += 4) {
        int   s0 = __shfl(c0r, j),     s1 = __shfl(c0r, j + 1);
        int   s2 = __shfl(c0r, j + 2), s3 = __shfl(c0r, j + 3);
        float w0 = __shfl(ex0, j),     w1 = __shfl(ex0, j + 1);
        float w2 = __shfl(ex0, j + 2), w3 = __shfl(ex0, j + 3);
        float2 h0 = H2[(size_t)s0 * 64 + lane];
        float2 h1 = H2[(size_t)s1 * 64 + lane];
        float2 h2 = H2[(size_t)s2 * 64 + lane];
        float2 h3 = H2[(size_t)s3 * 64 + lane];
        accx += w0 * h0.x; accy += w0 * h0.y;
        accx += w1 * h1.x; accy += w1 * h1.y;
        accx += w2 * h2.x; accy += w2 * h2.y;
        accx += w3 * h3.x; accy += w3 * h3.y;
    }
    for (; j < nfull; ++j) {
        int s = __shfl(c0r, j);
        float w = __shfl(ex0, j);
        float2 hv = H2[(size_t)s * 64 + lane];
        accx += w * hv.x; accy += w * hv.y;
    }
    for (int jj = 64; jj < degn; ++jj) {     // rare overflow path
        int s = col[beg + jj];
        float e = As[s] + adn;
        e = (e > 0.f) ? e : NEG_SLOPE * e;
        float w = __expf(e - m);
        float2 hv = H2[(size_t)s * 64 + lane];
        accx += w * hv.x; accy += w * hv.y;
    }

    float2 b2 = ((const float2*)bias)[lane];
    float ox = accx * inv + b2.x;
    float oy = accy * inv + b2.y;
    if (relu) { ox = fmaxf(ox, 0.f); oy = fmaxf(oy, 0.f); }
    float2 o2; o2.x = ox; o2.y = oy;
    ((float2*)Out)[(size_t)wid * 64 + lane] = o2;
}

// ---------------- FC head: (M x 128) @ (128 x 57) + b ----------------
// block = 256, tile 32 rows; W staged in LDS padded to 64 cols (32KB,
// shift/mask indexing, f%8 == cg%8 -> 2-way bank alias only).
__global__ __launch_bounds__(256) void fc_kernel(
    const float* __restrict__ H, const float* __restrict__ Wf,
    const float* __restrict__ bf, float* __restrict__ Out, int n)
{
    __shared__ float Wl[128 * 64];       // 32 KB
    int tid = threadIdx.x;
    for (int i = tid; i < 128 * 64; i += 256) {
        int k = i >> 6, c = i & 63;
        Wl[i] = (c < 57) ? Wf[k * 57 + c] : 0.f;
    }
    __syncthreads();

    int cg = tid & 15, rg = tid >> 4;
    int c0 = cg * 4;
    int row0 = blockIdx.x * 32;
    int r0 = row0 + rg * 2, r1 = r0 + 1;
    int rc0 = (r0 < n) ? r0 : (n - 1);
    int rc1 = (r1 < n) ? r1 : (n - 1);

    float acc[2][4];
    #pragma unroll
    for (int i = 0; i < 2; ++i)
        #pragma unroll
        for (int c = 0; c < 4; ++c) acc[i][c] = 0.f;

    const float* X0 = H + (size_t)rc0 * 128;
    const float* X1 = H + (size_t)rc1 * 128;
    const float4* Wl4 = (const float4*)Wl;

    for (int k = 0; k < 128; k += 4) {
        float4 xa = *(const float4*)(X0 + k);
        float4 xb = *(const float4*)(X1 + k);
        #pragma unroll
        for (int kk = 0; kk < 4; ++kk) {
            float4 wv = Wl4[(k + kk) * 16 + cg];
            float x0s = (kk == 0) ? xa.x : (kk == 1) ? xa.y : (kk == 2) ? xa.z : xa.w;
            float x1s = (kk == 0) ? xb.x : (kk == 1) ? xb.y : (kk == 2) ? xb.z : xb.w;
            acc[0][0] += x0s * wv.x; acc[0][1] += x0s * wv.y;
            acc[0][2] += x0s * wv.z; acc[0][3] += x0s * wv.w;
            acc[1][0] += x1s * wv.x; acc[1][1] += x1s * wv.y;
            acc[1][2] += x1s * wv.z; acc[1][3] += x1s * wv.w;
        }
    }

    #pragma unroll
    for (int i = 0; i < 2; ++i) {
        int r = r0 + i;
        if (r >= n) continue;
        #pragma unroll
        for (int cc = 0; cc < 4; ++cc) {
            int c = c0 + cc;
            if (c < 57) Out[(size_t)r * 57 + c] = acc[i][cc] + bf[c];
        }
    }
}

// ---------------- launch ----------------

extern "C" void kernel_launch(void* const* d_in, const int* in_sizes, int n_in,
                              void* d_out, int out_size, void* d_ws, size_t ws_size,
                              hipStream_t stream)
{
    const float* x   = (const float*)d_in[0];
    const int*   ei  = (const int*)d_in[1];
    const float* W1  = (const float*)d_in[2];
    const float* a1s = (const float*)d_in[3];
    const float* a1d = (const float*)d_in[4];
    const float* b1  = (const float*)d_in[5];
    const float* W2  = (const float*)d_in[6];
    const float* a2s = (const float*)d_in[7];
    const float* a2d = (const float*)d_in[8];
    const float* b2  = (const float*)d_in[9];
    const float* fcw = (const float*)d_in[10];
    const float* fcb = (const float*)d_in[11];
    float* out = (float*)d_out;

    int n = in_sizes[0] / 128;
    int E = in_sizes[1] / 2;
    int tot = E + n;
    int nchunks = (n + 1023) / 1024;

    char* ws = (char*)d_ws;
    size_t off = 0;
    auto alloc = [&](size_t bytes) -> void* {
        void* p = ws + off;
        off += (bytes + 255) & ~(size_t)255;
        return p;
    };
    float* hA     = (float*)alloc((size_t)n * 128 * 4);
    float* hB     = (float*)alloc((size_t)n * 128 * 4);
    float* As     = (float*)alloc((size_t)n * 4);
    float* Ad     = (float*)alloc((size_t)n * 4);
    int*   rowptr = (int*)alloc((size_t)(n + 1) * 4);
    int*   deg    = (int*)alloc((size_t)n * 4);
    int*   col    = (int*)alloc((size_t)tot * 4);
    int*   flag   = (int*)alloc(256);
    int*   csum   = (int*)alloc((size_t)64 * 4);

    hipMemsetAsync(deg, 0, (size_t)n * 4, stream);

    probe_i64_kernel<<<1, 64, 0, stream>>>(ei, E, flag);

    int nb = (tot + 255) / 256;
    count_deg_kernel<<<nb, 256, 0, stream>>>(ei, E, n, flag, deg);
    scan1_kernel<<<nchunks, 1024, 0, stream>>>(deg, rowptr, csum, n);
    scan2_kernel<<<1, 64, 0, stream>>>(csum, nchunks);
    if (nchunks > 1)
        scan3_kernel<<<nchunks - 1, 1024, 0, stream>>>(csum, rowptr, n);
    scatter_kernel<<<nb, 256, 0, stream>>>(ei, E, n, flag, rowptr, deg, col);

    int gb = (n + 31) / 32;
    int ab = (n + 3) / 4;

    // layer 1
    gemm_h_kernel<<<gb, 256, 0, stream>>>(x, W1, a1s, a1d, hA, As, Ad, n);
    gat_agg_kernel<<<ab, 256, 0, stream>>>(hA, As, Ad, rowptr, col, b1, hB, n, 1);
    // layer 2
    gemm_h_kernel<<<gb, 256, 0, stream>>>(hB, W2, a2s, a2d, hA, As, Ad, n);
    gat_agg_kernel<<<ab, 256, 0, stream>>>(hA, As, Ad, rowptr, col, b2, hB, n, 0);
    // head
    fc_kernel<<<gb, 256, 0, stream>>>(hB, fcw, fcb, out, n);
}

// Round 9
// 353.611 us; speedup vs baseline: 1.5004x; 1.0881x over previous
//
#include <hip/hip_runtime.h>
#include <hip/hip_fp16.h>

// ---------------------------------------------------------------------------
// ServiceGNN: 2-layer single-head GAT (+self-loops, segment softmax) + FC head
// N=50000, E=800000 (+N self loops), D_in=D_h=128, D_out=57.
// R6 (resubmitted; broker outages) = R3 (fp16 H gather path, dropped
// segment-max, x8 unroll) + CSR build rework: self-loops folded into scan
// (+1/node) and written directly to the last slot of each row; count/scatter
// vectorized 2 edges/lane via int2 (coalesced int64 reads, E-only atomics).
// ---------------------------------------------------------------------------

#define NEG_SLOPE 0.2f

struct __align__(8) half4_t { __half2 a, b; };

// ---------------- int64-vs-int32 edge_index probe ----------------
__global__ void probe_i64_kernel(const int* __restrict__ ei, int E, int* __restrict__ flag)
{
    int lane = threadIdx.x;              // blockDim = 64
    int v = 0;
    int lim = (E < 256) ? E : 256;
    for (int t = lane; t < lim; t += 64) v |= ei[2 * t + 1];
    #pragma unroll
    for (int o = 32; o >= 1; o >>= 1) v |= __shfl_xor(v, o);
    if (lane == 0) flag[0] = (v == 0) ? 1 : 0;
}

// ---------------- CSR build ----------------
// count: edges only (self-loops are added arithmetically in scan1).
// 2 edges per lane, int2 loads (8B-aligned for the int64 view always).
__global__ __launch_bounds__(256) void count_deg_kernel(
    const int* __restrict__ ei, int E, int n,
    const int* __restrict__ flag, int* __restrict__ deg)
{
    int is64 = flag[0];                  // uniform scalar branch
    int half = (E + 1) >> 1;
    int i2 = blockIdx.x * blockDim.x + threadIdx.x;
    if (i2 >= half) return;
    int e0 = 2 * i2;
    bool has1 = (e0 + 1) < E;
    int d0, d1 = 0;
    if (is64) {
        const int2* p = (const int2*)ei;         // int2 elem == one int64
        d0 = p[E + e0].x;
        if (has1) d1 = p[E + e0 + 1].x;
    } else {
        d0 = ei[E + e0];
        if (has1) d1 = ei[E + e0 + 1];
    }
    atomicAdd(&deg[d0], 1);
    if (has1) atomicAdd(&deg[d1], 1);
}

// scan pass 1: per-1024-chunk inclusive scan of (deg[i] + 1 self-loop).
__global__ __launch_bounds__(1024) void scan1_kernel(
    const int* __restrict__ deg, int* __restrict__ rowptr,
    int* __restrict__ csum, int n)
{
    __shared__ int wsum[16];
    int b = blockIdx.x, tid = threadIdx.x;
    int lane = tid & 63, wv = tid >> 6;
    int i = b * 1024 + tid;
    int v = (i < n) ? (deg[i] + 1) : 0;  // +1 = self-loop
    int s = v;
    #pragma unroll
    for (int off = 1; off < 64; off <<= 1) {
        int t = __shfl_up(s, off);
        if (lane >= off) s += t;
    }
    if (lane == 63) wsum[wv] = s;
    __syncthreads();
    if (wv == 0) {
        int ws = (lane < 16) ? wsum[lane] : 0;
        #pragma unroll
        for (int off = 1; off < 16; off <<= 1) {
            int t = __shfl_up(ws, off);
            if (lane >= off) ws += t;
        }
        if (lane < 16) wsum[lane] = ws;
    }
    __syncthreads();
    int woff = (wv == 0) ? 0 : wsum[wv - 1];
    int incl = woff + s;                 // chunk-local inclusive scan
    if (i < n) rowptr[i + 1] = incl;
    if (tid == 1023) csum[b] = incl;     // chunk total (OOB lanes added 0)
    if (b == 0 && tid == 0) rowptr[0] = 0;
}

// scan pass 2: one wave scans the <=64 chunk totals (inclusive).
__global__ void scan2_kernel(int* __restrict__ csum, int nb)
{
    int lane = threadIdx.x;              // blockDim = 64
    int v = (lane < nb) ? csum[lane] : 0;
    #pragma unroll
    for (int off = 1; off < 64; off <<= 1) {
        int t = __shfl_up(v, off);
        if (lane >= off) v += t;
    }
    if (lane < nb) csum[lane] = v;
}

// scan pass 3: add chunk base to chunks 1..nb-1.
__global__ __launch_bounds__(1024) void scan3_kernel(
    const int* __restrict__ csum, int* __restrict__ rowptr, int n)
{
    int b = blockIdx.x + 1;
    int i = b * 1024 + threadIdx.x;
    if (i < n) rowptr[i + 1] += csum[b - 1];
}

// scatter: 2 edges/lane (int2 loads); edges fill slots deg-1..0 of each row
// via atomicSub (deg holds edge-only counts); self-loop goes to the LAST
// slot (rowptr[d+1]-1) directly, handled by the tail thread range.
__global__ __launch_bounds__(256) void scatter_kernel(
    const int* __restrict__ ei, int E, int n,
    const int* __restrict__ flag,
    const int* __restrict__ rowptr, int* __restrict__ deg, int* __restrict__ col)
{
    int is64 = flag[0];
    int half = (E + 1) >> 1;
    int i2 = blockIdx.x * blockDim.x + threadIdx.x;
    if (i2 < half) {
        int e0 = 2 * i2;
        bool has1 = (e0 + 1) < E;
        int s0, d0, s1 = 0, d1 = 0;
        if (is64) {
            const int2* p = (const int2*)ei;
            s0 = p[e0].x;     d0 = p[E + e0].x;
            if (has1) { s1 = p[e0 + 1].x; d1 = p[E + e0 + 1].x; }
        } else {
            s0 = ei[e0];      d0 = ei[E + e0];
            if (has1) { s1 = ei[e0 + 1];  d1 = ei[E + e0 + 1]; }
        }
        int pos0 = atomicSub(&deg[d0], 1) - 1;
        col[rowptr[d0] + pos0] = s0;
        if (has1) {
            int pos1 = atomicSub(&deg[d1], 1) - 1;
            col[rowptr[d1] + pos1] = s1;
        }
    } else {
        int d = i2 - half;                   // self-loop writes
        if (d < n) col[rowptr[d + 1] - 1] = d;
    }
}

// ---------------- GEMM (M x 128 @ 128 x 128) with fused alpha dots ----------
// block = 256 threads, tile 32 rows x 128 cols; per-thread 2 rows x 8 cols.
// K split in two 64-k phases -> 32KB LDS W stage. Output H stored as fp16
// (its only consumer is the per-edge gather). Alphas from fp32 accumulators.
__global__ __launch_bounds__(256) void gemm_h_kernel(
    const float* __restrict__ X, const float* __restrict__ W,
    const float* __restrict__ asv, const float* __restrict__ adv,
    __half* __restrict__ H16, float* __restrict__ As, float* __restrict__ Ad, int n)
{
    __shared__ float Wl[64 * 128];       // 32 KB
    int tid = threadIdx.x;
    int cg = tid & 15, rg = tid >> 4;
    int row0 = blockIdx.x * 32;
    int r0 = row0 + rg * 2, r1 = r0 + 1;
    int rc0 = (r0 < n) ? r0 : (n - 1);   // clamped load rows (branch-free)
    int rc1 = (r1 < n) ? r1 : (n - 1);

    float acc[2][8];
    #pragma unroll
    for (int i = 0; i < 2; ++i)
        #pragma unroll
        for (int c = 0; c < 8; ++c) acc[i][c] = 0.f;

    const float4* Wl4 = (const float4*)Wl;

    #pragma unroll
    for (int p = 0; p < 2; ++p) {
        {   // stage W[p*64 .. p*64+63][:] -> 2048 float4s
            const float4* W4 = (const float4*)(W + p * 64 * 128);
            float4* Wl4w = (float4*)Wl;
            #pragma unroll
            for (int t = 0; t < 8; ++t) Wl4w[tid + t * 256] = W4[tid + t * 256];
        }
        __syncthreads();

        const float* X0 = X + (size_t)rc0 * 128 + p * 64;
        const float* X1 = X + (size_t)rc1 * 128 + p * 64;
        for (int k = 0; k < 64; k += 4) {
            float4 xa = *(const float4*)(X0 + k);
            float4 xb = *(const float4*)(X1 + k);
            #pragma unroll
            for (int kk = 0; kk < 4; ++kk) {
                float4 wA = Wl4[(k + kk) * 32 + cg];
                float4 wB = Wl4[(k + kk) * 32 + 16 + cg];
                float x0s = (kk == 0) ? xa.x : (kk == 1) ? xa.y : (kk == 2) ? xa.z : xa.w;
                float x1s = (kk == 0) ? xb.x : (kk == 1) ? xb.y : (kk == 2) ? xb.z : xb.w;
                acc[0][0] += x0s * wA.x; acc[0][1] += x0s * wA.y;
                acc[0][2] += x0s * wA.z; acc[0][3] += x0s * wA.w;
                acc[0][4] += x0s * wB.x; acc[0][5] += x0s * wB.y;
                acc[0][6] += x0s * wB.z; acc[0][7] += x0s * wB.w;
                acc[1][0] += x1s * wA.x; acc[1][1] += x1s * wA.y;
                acc[1][2] += x1s * wA.z; acc[1][3] += x1s * wA.w;
                acc[1][4] += x1s * wB.x; acc[1][5] += x1s * wB.y;
                acc[1][6] += x1s * wB.z; acc[1][7] += x1s * wB.w;
            }
        }
        __syncthreads();
    }

    // fused alpha epilogue (cols {cg*4..+3} and {64+cg*4..+3})
    float4 asA = *(const float4*)(asv + cg * 4);
    float4 asB = *(const float4*)(asv + 64 + cg * 4);
    float4 adA = *(const float4*)(adv + cg * 4);
    float4 adB = *(const float4*)(adv + 64 + cg * 4);

    #pragma unroll
    for (int i = 0; i < 2; ++i) {
        int r = r0 + i;
        float ps = acc[i][0] * asA.x + acc[i][1] * asA.y + acc[i][2] * asA.z + acc[i][3] * asA.w
                 + acc[i][4] * asB.x + acc[i][5] * asB.y + acc[i][6] * asB.z + acc[i][7] * asB.w;
        float pd = acc[i][0] * adA.x + acc[i][1] * adA.y + acc[i][2] * adA.z + acc[i][3] * adA.w
                 + acc[i][4] * adB.x + acc[i][5] * adB.y + acc[i][6] * adB.z + acc[i][7] * adB.w;
        #pragma unroll
        for (int mask = 8; mask >= 1; mask >>= 1) {   // reduce across the 16 cgs
            ps += __shfl_xor(ps, mask);
            pd += __shfl_xor(pd, mask);
        }
        if (r < n) {
            half4_t hlo, hhi;
            hlo.a = __floats2half2_rn(acc[i][0], acc[i][1]);
            hlo.b = __floats2half2_rn(acc[i][2], acc[i][3]);
            hhi.a = __floats2half2_rn(acc[i][4], acc[i][5]);
            hhi.b = __floats2half2_rn(acc[i][6], acc[i][7]);
            *(half4_t*)(H16 + (size_t)r * 128 + cg * 4)      = hlo;
            *(half4_t*)(H16 + (size_t)r * 128 + 64 + cg * 4) = hhi;
            if (cg == 0) { As[r] = ps; Ad[r] = pd; }
        }
    }
}

// ---------------- GAT aggregation: one wave per dst node ----------------
// No segment-max: softmax is shift-invariant and logits are bounded (|e|<~15),
// so exp(e) cannot overflow fp32. Gather reads fp16 (4 B/lane/edge).
__global__ __launch_bounds__(256) void gat_agg_kernel(
    const __half* __restrict__ H16, const float* __restrict__ As, const float* __restrict__ Ad,
    const int* __restrict__ rowptr, const int* __restrict__ col,
    const float* __restrict__ bias, float* __restrict__ Out, int n, int relu)
{
    int wid = (blockIdx.x * blockDim.x + threadIdx.x) >> 6;
    int lane = threadIdx.x & 63;
    if (wid >= n) return;

    int beg = rowptr[wid], end = rowptr[wid + 1];
    int degn = end - beg;
    float adn = Ad[wid];

    int c0r = 0;
    if (lane < degn) c0r = col[beg + lane];

    // per-lane weight (first 64 edges) + denominator
    float ex0 = 0.f;
    if (lane < degn) {
        float e = As[c0r] + adn;
        e = (e > 0.f) ? e : NEG_SLOPE * e;
        ex0 = __expf(e);
    }
    float den = ex0;
    for (int j = beg + lane + 64; j < end; j += 64) {
        float e = As[col[j]] + adn;
        e = (e > 0.f) ? e : NEG_SLOPE * e;
        den += __expf(e);
    }
    #pragma unroll
    for (int o = 32; o >= 1; o >>= 1) den += __shfl_xor(den, o);
    float inv = 1.f / den;

    // weighted gather-aggregate, 8 edges in flight per wave (256 B/edge).
    const __half2* H2 = (const __half2*)H16;
    float accx = 0.f, accy = 0.f;
    int nfull = (degn < 64) ? degn : 64;
    int j = 0;
    for (; j + 8 <= nfull; j += 8) {
        int ss[8]; float ww[8]; __half2 hh[8];
        #pragma unroll
        for (int u = 0; u < 8; ++u) { ss[u] = __shfl(c0r, j + u); ww[u] = __shfl(ex0, j + u); }
        #pragma unroll
        for (int u = 0; u < 8; ++u) { hh[u] = H2[(size_t)ss[u] * 64 + lane]; }
        #pragma unroll
        for (int u = 0; u < 8; ++u) {
            float2 f = __half22float2(hh[u]);
            accx += ww[u] * f.x; accy += ww[u] * f.y;
        }
    }
    for (; j < nfull; ++j) {
        int s = __shfl(c0r, j);
        float w = __shfl(ex0, j);
        float2 f = __half22float2(H2[(size_t)s * 64 + lane]);
        accx += w * f.x; accy += w * f.y;
    }
    for (int jj = 64; jj < degn; ++jj) {     // rare overflow path
        int s = col[beg + jj];
        float e = As[s] + adn;
        e = (e > 0.f) ? e : NEG_SLOPE * e;
        float w = __expf(e);
        float2 f = __half22float2(H2[(size_t)s * 64 + lane]);
        accx += w * f.x; accy += w * f.y;
    }

    float2 b2 = ((const float2*)bias)[lane];
    float ox = accx * inv + b2.x;
    float oy = accy * inv + b2.y;
    if (relu) { ox = fmaxf(ox, 0.f); oy = fmaxf(oy, 0.f); }
    float2 o2; o2.x = ox; o2.y = oy;
    ((float2*)Out)[(size_t)wid * 64 + lane] = o2;
}

// ---------------- FC head: (M x 128) @ (128 x 57) + b ----------------
// block = 256, tile 32 rows; W staged in LDS padded to 64 cols (32KB).
__global__ __launch_bounds__(256) void fc_kernel(
    const float* __restrict__ H, const float* __restrict__ Wf,
    const float* __restrict__ bf, float* __restrict__ Out, int n)
{
    __shared__ float Wl[128 * 64];       // 32 KB
    int tid = threadIdx.x;
    for (int i = tid; i < 128 * 64; i += 256) {
        int k = i >> 6, c = i & 63;
        Wl[i] = (c < 57) ? Wf[k * 57 + c] : 0.f;
    }
    __syncthreads();

    int cg = tid & 15, rg = tid >> 4;
    int c0 = cg * 4;
    int row0 = blockIdx.x * 32;
    int r0 = row0 + rg * 2, r1 = r0 + 1;
    int rc0 = (r0 < n) ? r0 : (n - 1);
    int rc1 = (r1 < n) ? r1 : (n - 1);

    float acc[2][4];
    #pragma unroll
    for (int i = 0; i < 2; ++i)
        #pragma unroll
        for (int c = 0; c < 4; ++c) acc[i][c] = 0.f;

    const float* X0 = H + (size_t)rc0 * 128;
    const float* X1 = H + (size_t)rc1 * 128;
    const float4* Wl4 = (const float4*)Wl;

    for (int k = 0; k < 128; k += 4) {
        float4 xa = *(const float4*)(X0 + k);
        float4 xb = *(const float4*)(X1 + k);
        #pragma unroll
        for (int kk = 0; kk < 4; ++kk) {
            float4 wv = Wl4[(k + kk) * 16 + cg];
            float x0s = (kk == 0) ? xa.x : (kk == 1) ? xa.y : (kk == 2) ? xa.z : xa.w;
            float x1s = (kk == 0) ? xb.x : (kk == 1) ? xb.y : (kk == 2) ? xb.z : xb.w;
            acc[0][0] += x0s * wv.x; acc[0][1] += x0s * wv.y;
            acc[0][2] += x0s * wv.z; acc[0][3] += x0s * wv.w;
            acc[1][0] += x1s * wv.x; acc[1][1] += x1s * wv.y;
            acc[1][2] += x1s * wv.z; acc[1][3] += x1s * wv.w;
        }
    }

    #pragma unroll
    for (int i = 0; i < 2; ++i) {
        int r = r0 + i;
        if (r >= n) continue;
        #pragma unroll
        for (int cc = 0; cc < 4; ++cc) {
            int c = c0 + cc;
            if (c < 57) Out[(size_t)r * 57 + c] = acc[i][cc] + bf[c];
        }
    }
}

// ---------------- launch ----------------

extern "C" void kernel_launch(void* const* d_in, const int* in_sizes, int n_in,
                              void* d_out, int out_size, void* d_ws, size_t ws_size,
                              hipStream_t stream)
{
    const float* x   = (const float*)d_in[0];
    const int*   ei  = (const int*)d_in[1];
    const float* W1  = (const float*)d_in[2];
    const float* a1s = (const float*)d_in[3];
    const float* a1d = (const float*)d_in[4];
    const float* b1  = (const float*)d_in[5];
    const float* W2  = (const float*)d_in[6];
    const float* a2s = (const float*)d_in[7];
    const float* a2d = (const float*)d_in[8];
    const float* b2  = (const float*)d_in[9];
    const float* fcw = (const float*)d_in[10];
    const float* fcb = (const float*)d_in[11];
    float* out = (float*)d_out;

    int n = in_sizes[0] / 128;
    int E = in_sizes[1] / 2;
    int tot = E + n;
    int nchunks = (n + 1023) / 1024;
    int half = (E + 1) >> 1;

    char* ws = (char*)d_ws;
    size_t off = 0;
    auto alloc = [&](size_t bytes) -> void* {
        void* p = ws + off;
        off += (bytes + 255) & ~(size_t)255;
        return p;
    };
    __half* h16   = (__half*)alloc((size_t)n * 128 * 2);   // gemm out (both layers)
    float* hF     = (float*)alloc((size_t)n * 128 * 4);    // agg out (both layers)
    float* As     = (float*)alloc((size_t)n * 4);
    float* Ad     = (float*)alloc((size_t)n * 4);
    int*   rowptr = (int*)alloc((size_t)(n + 1) * 4);
    int*   deg    = (int*)alloc((size_t)n * 4);
    int*   col    = (int*)alloc((size_t)tot * 4);
    int*   flag   = (int*)alloc(256);
    int*   csum   = (int*)alloc((size_t)64 * 4);

    hipMemsetAsync(deg, 0, (size_t)n * 4, stream);

    probe_i64_kernel<<<1, 64, 0, stream>>>(ei, E, flag);

    int cb = (half + 255) / 256;
    count_deg_kernel<<<cb, 256, 0, stream>>>(ei, E, n, flag, deg);
    scan1_kernel<<<nchunks, 1024, 0, stream>>>(deg, rowptr, csum, n);
    scan2_kernel<<<1, 64, 0, stream>>>(csum, nchunks);
    if (nchunks > 1)
        scan3_kernel<<<nchunks - 1, 1024, 0, stream>>>(csum, rowptr, n);
    int sb = (half + n + 255) / 256;
    scatter_kernel<<<sb, 256, 0, stream>>>(ei, E, n, flag, rowptr, deg, col);

    int gb = (n + 31) / 32;
    int ab = (n + 3) / 4;

    // layer 1
    gemm_h_kernel<<<gb, 256, 0, stream>>>(x, W1, a1s, a1d, h16, As, Ad, n);
    gat_agg_kernel<<<ab, 256, 0, stream>>>(h16, As, Ad, rowptr, col, b1, hF, n, 1);
    // layer 2 (h16 reused; hF consumed by gemm before agg overwrites it)
    gemm_h_kernel<<<gb, 256, 0, stream>>>(hF, W2, a2s, a2d, h16, As, Ad, n);
    gat_agg_kernel<<<ab, 256, 0, stream>>>(h16, As, Ad, rowptr, col, b2, hF, n, 0);
    // head
    fc_kernel<<<gb, 256, 0, stream>>>(hF, fcw, fcb, out, n);
}

// Round 10
// 336.776 us; speedup vs baseline: 1.5754x; 1.0500x over previous
//
#include <hip/hip_runtime.h>
#include <hip/hip_fp16.h>

// ---------------------------------------------------------------------------
// ServiceGNN: 2-layer single-head GAT (+self-loops, segment softmax) + FC head
// N=50000, E=800000 (+N self loops), D_in=D_h=128, D_out=57.
// R10 = R6 (fp16 H, dropped segment-max, CSR self-loop fold; verified
// absmax 3.9e-3) + count fused into gemm1 dispatch (independent work,
// complementary pipes) + count/scatter widened to 4 edges/lane (int4).
// ---------------------------------------------------------------------------

#define NEG_SLOPE 0.2f

struct __align__(8) half4_t { __half2 a, b; };

// ---------------- int64-vs-int32 edge_index probe ----------------
__global__ void probe_i64_kernel(const int* __restrict__ ei, int E, int* __restrict__ flag)
{
    int lane = threadIdx.x;              // blockDim = 64
    int v = 0;
    int lim = (E < 256) ? E : 256;
    for (int t = lane; t < lim; t += 64) v |= ei[2 * t + 1];
    #pragma unroll
    for (int o = 32; o >= 1; o >>= 1) v |= __shfl_xor(v, o);
    if (lane == 0) flag[0] = (v == 0) ? 1 : 0;
}

// ---------------- fused: count_deg (4 edges/lane) || gemm1(+alphas) --------
// blocks [0, cntBlocks)           : degree count (atomics, latency-bound)
// blocks [cntBlocks, cntBlocks+gb): 32x128 GEMM tile (VALU/LDS-bound)
// Independent work in one dispatch -> concurrent execution on the CUs.
__global__ __launch_bounds__(256) void fused_count_gemm_kernel(
    const int* __restrict__ ei, int E, int n,
    const int* __restrict__ flag, int* __restrict__ deg, int cntBlocks,
    const float* __restrict__ X, const float* __restrict__ W,
    const float* __restrict__ asv, const float* __restrict__ adv,
    __half* __restrict__ H16, float* __restrict__ As, float* __restrict__ Ad)
{
    __shared__ float Wl[64 * 128];       // 32 KB (used by gemm part only)

    if ((int)blockIdx.x < cntBlocks) {
        // ---- count part: 4 edges per lane, int4 loads ----
        int is64 = flag[0];
        int base = (blockIdx.x * 256 + threadIdx.x) * 4;
        if (base >= E) return;
        int d[4];
        int cnt;
        if (base + 4 <= E) {
            cnt = 4;
            if (is64) {
                const int4* q = (const int4*)ei;     // int4 = 2 int64
                int4 a = q[(E + base) >> 1];
                int4 b = q[((E + base) >> 1) + 1];
                d[0] = a.x; d[1] = a.z; d[2] = b.x; d[3] = b.z;
            } else {
                int4 a = *(const int4*)(ei + E + base);
                d[0] = a.x; d[1] = a.y; d[2] = a.z; d[3] = a.w;
            }
        } else {
            cnt = E - base;
            for (int u = 0; u < cnt; ++u)
                d[u] = is64 ? ei[2 * (E + base + u)] : ei[E + base + u];
        }
        #pragma unroll
        for (int u = 0; u < 4; ++u)
            if (u < cnt) atomicAdd(&deg[d[u]], 1);
        return;
    }

    // ---- gemm part ----
    int tid = threadIdx.x;
    int cg = tid & 15, rg = tid >> 4;
    int row0 = ((int)blockIdx.x - cntBlocks) * 32;
    int r0 = row0 + rg * 2, r1 = r0 + 1;
    int rc0 = (r0 < n) ? r0 : (n - 1);
    int rc1 = (r1 < n) ? r1 : (n - 1);

    float acc[2][8];
    #pragma unroll
    for (int i = 0; i < 2; ++i)
        #pragma unroll
        for (int c = 0; c < 8; ++c) acc[i][c] = 0.f;

    const float4* Wl4 = (const float4*)Wl;

    #pragma unroll
    for (int p = 0; p < 2; ++p) {
        {
            const float4* W4 = (const float4*)(W + p * 64 * 128);
            float4* Wl4w = (float4*)Wl;
            #pragma unroll
            for (int t = 0; t < 8; ++t) Wl4w[tid + t * 256] = W4[tid + t * 256];
        }
        __syncthreads();

        const float* X0 = X + (size_t)rc0 * 128 + p * 64;
        const float* X1 = X + (size_t)rc1 * 128 + p * 64;
        for (int k = 0; k < 64; k += 4) {
            float4 xa = *(const float4*)(X0 + k);
            float4 xb = *(const float4*)(X1 + k);
            #pragma unroll
            for (int kk = 0; kk < 4; ++kk) {
                float4 wA = Wl4[(k + kk) * 32 + cg];
                float4 wB = Wl4[(k + kk) * 32 + 16 + cg];
                float x0s = (kk == 0) ? xa.x : (kk == 1) ? xa.y : (kk == 2) ? xa.z : xa.w;
                float x1s = (kk == 0) ? xb.x : (kk == 1) ? xb.y : (kk == 2) ? xb.z : xb.w;
                acc[0][0] += x0s * wA.x; acc[0][1] += x0s * wA.y;
                acc[0][2] += x0s * wA.z; acc[0][3] += x0s * wA.w;
                acc[0][4] += x0s * wB.x; acc[0][5] += x0s * wB.y;
                acc[0][6] += x0s * wB.z; acc[0][7] += x0s * wB.w;
                acc[1][0] += x1s * wA.x; acc[1][1] += x1s * wA.y;
                acc[1][2] += x1s * wA.z; acc[1][3] += x1s * wA.w;
                acc[1][4] += x1s * wB.x; acc[1][5] += x1s * wB.y;
                acc[1][6] += x1s * wB.z; acc[1][7] += x1s * wB.w;
            }
        }
        __syncthreads();
    }

    float4 asA = *(const float4*)(asv + cg * 4);
    float4 asB = *(const float4*)(asv + 64 + cg * 4);
    float4 adA = *(const float4*)(adv + cg * 4);
    float4 adB = *(const float4*)(adv + 64 + cg * 4);

    #pragma unroll
    for (int i = 0; i < 2; ++i) {
        int r = r0 + i;
        float ps = acc[i][0] * asA.x + acc[i][1] * asA.y + acc[i][2] * asA.z + acc[i][3] * asA.w
                 + acc[i][4] * asB.x + acc[i][5] * asB.y + acc[i][6] * asB.z + acc[i][7] * asB.w;
        float pd = acc[i][0] * adA.x + acc[i][1] * adA.y + acc[i][2] * adA.z + acc[i][3] * adA.w
                 + acc[i][4] * adB.x + acc[i][5] * adB.y + acc[i][6] * adB.z + acc[i][7] * adB.w;
        #pragma unroll
        for (int mask = 8; mask >= 1; mask >>= 1) {
            ps += __shfl_xor(ps, mask);
            pd += __shfl_xor(pd, mask);
        }
        if (r < n) {
            half4_t hlo, hhi;
            hlo.a = __floats2half2_rn(acc[i][0], acc[i][1]);
            hlo.b = __floats2half2_rn(acc[i][2], acc[i][3]);
            hhi.a = __floats2half2_rn(acc[i][4], acc[i][5]);
            hhi.b = __floats2half2_rn(acc[i][6], acc[i][7]);
            *(half4_t*)(H16 + (size_t)r * 128 + cg * 4)      = hlo;
            *(half4_t*)(H16 + (size_t)r * 128 + 64 + cg * 4) = hhi;
            if (cg == 0) { As[r] = ps; Ad[r] = pd; }
        }
    }
}

// scan pass 1: per-1024-chunk inclusive scan of (deg[i] + 1 self-loop).
__global__ __launch_bounds__(1024) void scan1_kernel(
    const int* __restrict__ deg, int* __restrict__ rowptr,
    int* __restrict__ csum, int n)
{
    __shared__ int wsum[16];
    int b = blockIdx.x, tid = threadIdx.x;
    int lane = tid & 63, wv = tid >> 6;
    int i = b * 1024 + tid;
    int v = (i < n) ? (deg[i] + 1) : 0;  // +1 = self-loop
    int s = v;
    #pragma unroll
    for (int off = 1; off < 64; off <<= 1) {
        int t = __shfl_up(s, off);
        if (lane >= off) s += t;
    }
    if (lane == 63) wsum[wv] = s;
    __syncthreads();
    if (wv == 0) {
        int ws = (lane < 16) ? wsum[lane] : 0;
        #pragma unroll
        for (int off = 1; off < 16; off <<= 1) {
            int t = __shfl_up(ws, off);
            if (lane >= off) ws += t;
        }
        if (lane < 16) wsum[lane] = ws;
    }
    __syncthreads();
    int woff = (wv == 0) ? 0 : wsum[wv - 1];
    int incl = woff + s;
    if (i < n) rowptr[i + 1] = incl;
    if (tid == 1023) csum[b] = incl;
    if (b == 0 && tid == 0) rowptr[0] = 0;
}

// scan pass 2: one wave scans the <=64 chunk totals (inclusive).
__global__ void scan2_kernel(int* __restrict__ csum, int nb)
{
    int lane = threadIdx.x;              // blockDim = 64
    int v = (lane < nb) ? csum[lane] : 0;
    #pragma unroll
    for (int off = 1; off < 64; off <<= 1) {
        int t = __shfl_up(v, off);
        if (lane >= off) v += t;
    }
    if (lane < nb) csum[lane] = v;
}

// scan pass 3: add chunk base to chunks 1..nb-1.
__global__ __launch_bounds__(1024) void scan3_kernel(
    const int* __restrict__ csum, int* __restrict__ rowptr, int n)
{
    int b = blockIdx.x + 1;
    int i = b * 1024 + threadIdx.x;
    if (i < n) rowptr[i + 1] += csum[b - 1];
}

// scatter: 4 edges/lane (int4 loads); edges fill slots deg-1..0 of each row
// via atomicSub; self-loop goes to the LAST slot (rowptr[d+1]-1) directly.
__global__ __launch_bounds__(256) void scatter_kernel(
    const int* __restrict__ ei, int E, int n,
    const int* __restrict__ flag,
    const int* __restrict__ rowptr, int* __restrict__ deg, int* __restrict__ col)
{
    int is64 = flag[0];
    int quarter = (E + 3) >> 2;
    int iq = blockIdx.x * blockDim.x + threadIdx.x;
    if (iq < quarter) {
        int base = iq * 4;
        int s[4], d[4];
        int cnt;
        if (base + 4 <= E) {
            cnt = 4;
            if (is64) {
                const int4* q = (const int4*)ei;
                int4 sa = q[base >> 1];
                int4 sb = q[(base >> 1) + 1];
                int4 da = q[(E + base) >> 1];
                int4 db = q[((E + base) >> 1) + 1];
                s[0] = sa.x; s[1] = sa.z; s[2] = sb.x; s[3] = sb.z;
                d[0] = da.x; d[1] = da.z; d[2] = db.x; d[3] = db.z;
            } else {
                int4 sa = *(const int4*)(ei + base);
                int4 da = *(const int4*)(ei + E + base);
                s[0] = sa.x; s[1] = sa.y; s[2] = sa.z; s[3] = sa.w;
                d[0] = da.x; d[1] = da.y; d[2] = da.z; d[3] = da.w;
            }
        } else {
            cnt = E - base;
            for (int u = 0; u < cnt; ++u) {
                if (is64) { s[u] = ei[2 * (base + u)]; d[u] = ei[2 * (E + base + u)]; }
                else      { s[u] = ei[base + u];       d[u] = ei[E + base + u]; }
            }
        }
        #pragma unroll
        for (int u = 0; u < 4; ++u) {
            if (u < cnt) {
                int pos = atomicSub(&deg[d[u]], 1) - 1;
                col[rowptr[d[u]] + pos] = s[u];
            }
        }
    } else {
        int dd = iq - quarter;               // self-loop writes
        if (dd < n) col[rowptr[dd + 1] - 1] = dd;
    }
}

// ---------------- standalone GEMM (layer 2) with fused alpha dots ----------
__global__ __launch_bounds__(256) void gemm_h_kernel(
    const float* __restrict__ X, const float* __restrict__ W,
    const float* __restrict__ asv, const float* __restrict__ adv,
    __half* __restrict__ H16, float* __restrict__ As, float* __restrict__ Ad, int n)
{
    __shared__ float Wl[64 * 128];       // 32 KB
    int tid = threadIdx.x;
    int cg = tid & 15, rg = tid >> 4;
    int row0 = blockIdx.x * 32;
    int r0 = row0 + rg * 2, r1 = r0 + 1;
    int rc0 = (r0 < n) ? r0 : (n - 1);
    int rc1 = (r1 < n) ? r1 : (n - 1);

    float acc[2][8];
    #pragma unroll
    for (int i = 0; i < 2; ++i)
        #pragma unroll
        for (int c = 0; c < 8; ++c) acc[i][c] = 0.f;

    const float4* Wl4 = (const float4*)Wl;

    #pragma unroll
    for (int p = 0; p < 2; ++p) {
        {
            const float4* W4 = (const float4*)(W + p * 64 * 128);
            float4* Wl4w = (float4*)Wl;
            #pragma unroll
            for (int t = 0; t < 8; ++t) Wl4w[tid + t * 256] = W4[tid + t * 256];
        }
        __syncthreads();

        const float* X0 = X + (size_t)rc0 * 128 + p * 64;
        const float* X1 = X + (size_t)rc1 * 128 + p * 64;
        for (int k = 0; k < 64; k += 4) {
            float4 xa = *(const float4*)(X0 + k);
            float4 xb = *(const float4*)(X1 + k);
            #pragma unroll
            for (int kk = 0; kk < 4; ++kk) {
                float4 wA = Wl4[(k + kk) * 32 + cg];
                float4 wB = Wl4[(k + kk) * 32 + 16 + cg];
                float x0s = (kk == 0) ? xa.x : (kk == 1) ? xa.y : (kk == 2) ? xa.z : xa.w;
                float x1s = (kk == 0) ? xb.x : (kk == 1) ? xb.y : (kk == 2) ? xb.z : xb.w;
                acc[0][0] += x0s * wA.x; acc[0][1] += x0s * wA.y;
                acc[0][2] += x0s * wA.z; acc[0][3] += x0s * wA.w;
                acc[0][4] += x0s * wB.x; acc[0][5] += x0s * wB.y;
                acc[0][6] += x0s * wB.z; acc[0][7] += x0s * wB.w;
                acc[1][0] += x1s * wA.x; acc[1][1] += x1s * wA.y;
                acc[1][2] += x1s * wA.z; acc[1][3] += x1s * wA.w;
                acc[1][4] += x1s * wB.x; acc[1][5] += x1s * wB.y;
                acc[1][6] += x1s * wB.z; acc[1][7] += x1s * wB.w;
            }
        }
        __syncthreads();
    }

    float4 asA = *(const float4*)(asv + cg * 4);
    float4 asB = *(const float4*)(asv + 64 + cg * 4);
    float4 adA = *(const float4*)(adv + cg * 4);
    float4 adB = *(const float4*)(adv + 64 + cg * 4);

    #pragma unroll
    for (int i = 0; i < 2; ++i) {
        int r = r0 + i;
        float ps = acc[i][0] * asA.x + acc[i][1] * asA.y + acc[i][2] * asA.z + acc[i][3] * asA.w
                 + acc[i][4] * asB.x + acc[i][5] * asB.y + acc[i][6] * asB.z + acc[i][7] * asB.w;
        float pd = acc[i][0] * adA.x + acc[i][1] * adA.y + acc[i][2] * adA.z + acc[i][3] * adA.w
                 + acc[i][4] * adB.x + acc[i][5] * adB.y + acc[i][6] * adB.z + acc[i][7] * adB.w;
        #pragma unroll
        for (int mask = 8; mask >= 1; mask >>= 1) {
            ps += __shfl_xor(ps, mask);
            pd += __shfl_xor(pd, mask);
        }
        if (r < n) {
            half4_t hlo, hhi;
            hlo.a = __floats2half2_rn(acc[i][0], acc[i][1]);
            hlo.b = __floats2half2_rn(acc[i][2], acc[i][3]);
            hhi.a = __floats2half2_rn(acc[i][4], acc[i][5]);
            hhi.b = __floats2half2_rn(acc[i][6], acc[i][7]);
            *(half4_t*)(H16 + (size_t)r * 128 + cg * 4)      = hlo;
            *(half4_t*)(H16 + (size_t)r * 128 + 64 + cg * 4) = hhi;
            if (cg == 0) { As[r] = ps; Ad[r] = pd; }
        }
    }
}

// ---------------- GAT aggregation: one wave per dst node ----------------
__global__ __launch_bounds__(256) void gat_agg_kernel(
    const __half* __restrict__ H16, const float* __restrict__ As, const float* __restrict__ Ad,
    const int* __restrict__ rowptr, const int* __restrict__ col,
    const float* __restrict__ bias, float* __restrict__ Out, int n, int relu)
{
    int wid = (blockIdx.x * blockDim.x + threadIdx.x) >> 6;
    int lane = threadIdx.x & 63;
    if (wid >= n) return;

    int beg = rowptr[wid], end = rowptr[wid + 1];
    int degn = end - beg;
    float adn = Ad[wid];

    int c0r = 0;
    if (lane < degn) c0r = col[beg + lane];

    float ex0 = 0.f;
    if (lane < degn) {
        float e = As[c0r] + adn;
        e = (e > 0.f) ? e : NEG_SLOPE * e;
        ex0 = __expf(e);
    }
    float den = ex0;
    for (int j = beg + lane + 64; j < end; j += 64) {
        float e = As[col[j]] + adn;
        e = (e > 0.f) ? e : NEG_SLOPE * e;
        den += __expf(e);
    }
    #pragma unroll
    for (int o = 32; o >= 1; o >>= 1) den += __shfl_xor(den, o);
    float inv = 1.f / den;

    const __half2* H2 = (const __half2*)H16;
    float accx = 0.f, accy = 0.f;
    int nfull = (degn < 64) ? degn : 64;
    int j = 0;
    for (; j + 8 <= nfull; j += 8) {
        int ss[8]; float ww[8]; __half2 hh[8];
        #pragma unroll
        for (int u = 0; u < 8; ++u) { ss[u] = __shfl(c0r, j + u); ww[u] = __shfl(ex0, j + u); }
        #pragma unroll
        for (int u = 0; u < 8; ++u) { hh[u] = H2[(size_t)ss[u] * 64 + lane]; }
        #pragma unroll
        for (int u = 0; u < 8; ++u) {
            float2 f = __half22float2(hh[u]);
            accx += ww[u] * f.x; accy += ww[u] * f.y;
        }
    }
    for (; j < nfull; ++j) {
        int s = __shfl(c0r, j);
        float w = __shfl(ex0, j);
        float2 f = __half22float2(H2[(size_t)s * 64 + lane]);
        accx += w * f.x; accy += w * f.y;
    }
    for (int jj = 64; jj < degn; ++jj) {
        int s = col[beg + jj];
        float e = As[s] + adn;
        e = (e > 0.f) ? e : NEG_SLOPE * e;
        float w = __expf(e);
        float2 f = __half22float2(H2[(size_t)s * 64 + lane]);
        accx += w * f.x; accy += w * f.y;
    }

    float2 b2 = ((const float2*)bias)[lane];
    float ox = accx * inv + b2.x;
    float oy = accy * inv + b2.y;
    if (relu) { ox = fmaxf(ox, 0.f); oy = fmaxf(oy, 0.f); }
    float2 o2; o2.x = ox; o2.y = oy;
    ((float2*)Out)[(size_t)wid * 64 + lane] = o2;
}

// ---------------- FC head: (M x 128) @ (128 x 57) + b ----------------
__global__ __launch_bounds__(256) void fc_kernel(
    const float* __restrict__ H, const float* __restrict__ Wf,
    const float* __restrict__ bf, float* __restrict__ Out, int n)
{
    __shared__ float Wl[128 * 64];       // 32 KB
    int tid = threadIdx.x;
    for (int i = tid; i < 128 * 64; i += 256) {
        int k = i >> 6, c = i & 63;
        Wl[i] = (c < 57) ? Wf[k * 57 + c] : 0.f;
    }
    __syncthreads();

    int cg = tid & 15, rg = tid >> 4;
    int c0 = cg * 4;
    int row0 = blockIdx.x * 32;
    int r0 = row0 + rg * 2, r1 = r0 + 1;
    int rc0 = (r0 < n) ? r0 : (n - 1);
    int rc1 = (r1 < n) ? r1 : (n - 1);

    float acc[2][4];
    #pragma unroll
    for (int i = 0; i < 2; ++i)
        #pragma unroll
        for (int c = 0; c < 4; ++c) acc[i][c] = 0.f;

    const float* X0 = H + (size_t)rc0 * 128;
    const float* X1 = H + (size_t)rc1 * 128;
    const float4* Wl4 = (const float4*)Wl;

    for (int k = 0; k < 128; k += 4) {
        float4 xa = *(const float4*)(X0 + k);
        float4 xb = *(const float4*)(X1 + k);
        #pragma unroll
        for (int kk = 0; kk < 4; ++kk) {
            float4 wv = Wl4[(k + kk) * 16 + cg];
            float x0s = (kk == 0) ? xa.x : (kk == 1) ? xa.y : (kk == 2) ? xa.z : xa.w;
            float x1s = (kk == 0) ? xb.x : (kk == 1) ? xb.y : (kk == 2) ? xb.z : xb.w;
            acc[0][0] += x0s * wv.x; acc[0][1] += x0s * wv.y;
            acc[0][2] += x0s * wv.z; acc[0][3] += x0s * wv.w;
            acc[1][0] += x1s * wv.x; acc[1][1] += x1s * wv.y;
            acc[1][2] += x1s * wv.z; acc[1][3] += x1s * wv.w;
        }
    }

    #pragma unroll
    for (int i = 0; i < 2; ++i) {
        int r = r0 + i;
        if (r >= n) continue;
        #pragma unroll
        for (int cc = 0; cc < 4; ++cc) {
            int c = c0 + cc;
            if (c < 57) Out[(size_t)r * 57 + c] = acc[i][cc] + bf[c];
        }
    }
}

// ---------------- launch ----------------

extern "C" void kernel_launch(void* const* d_in, const int* in_sizes, int n_in,
                              void* d_out, int out_size, void* d_ws, size_t ws_size,
                              hipStream_t stream)
{
    const float* x   = (const float*)d_in[0];
    const int*   ei  = (const int*)d_in[1];
    const float* W1  = (const float*)d_in[2];
    const float* a1s = (const float*)d_in[3];
    const float* a1d = (const float*)d_in[4];
    const float* b1  = (const float*)d_in[5];
    const float* W2  = (const float*)d_in[6];
    const float* a2s = (const float*)d_in[7];
    const float* a2d = (const float*)d_in[8];
    const float* b2  = (const float*)d_in[9];
    const float* fcw = (const float*)d_in[10];
    const float* fcb = (const float*)d_in[11];
    float* out = (float*)d_out;

    int n = in_sizes[0] / 128;
    int E = in_sizes[1] / 2;
    int tot = E + n;
    int nchunks = (n + 1023) / 1024;
    int quarter = (E + 3) >> 2;

    char* ws = (char*)d_ws;
    size_t off = 0;
    auto alloc = [&](size_t bytes) -> void* {
        void* p = ws + off;
        off += (bytes + 255) & ~(size_t)255;
        return p;
    };
    __half* h16   = (__half*)alloc((size_t)n * 128 * 2);   // gemm out (both layers)
    float* hF     = (float*)alloc((size_t)n * 128 * 4);    // agg out (both layers)
    float* As     = (float*)alloc((size_t)n * 4);
    float* Ad     = (float*)alloc((size_t)n * 4);
    int*   rowptr = (int*)alloc((size_t)(n + 1) * 4);
    int*   deg    = (int*)alloc((size_t)n * 4);
    int*   col    = (int*)alloc((size_t)tot * 4);
    int*   flag   = (int*)alloc(256);
    int*   csum   = (int*)alloc((size_t)64 * 4);

    hipMemsetAsync(deg, 0, (size_t)n * 4, stream);

    probe_i64_kernel<<<1, 64, 0, stream>>>(ei, E, flag);

    int gb = (n + 31) / 32;
    int cntBlocks = (quarter + 255) / 256;

    // count (atomics) || gemm1 (VALU/LDS) in one dispatch; count blocks first
    fused_count_gemm_kernel<<<cntBlocks + gb, 256, 0, stream>>>(
        ei, E, n, flag, deg, cntBlocks, x, W1, a1s, a1d, h16, As, Ad);

    scan1_kernel<<<nchunks, 1024, 0, stream>>>(deg, rowptr, csum, n);
    scan2_kernel<<<1, 64, 0, stream>>>(csum, nchunks);
    if (nchunks > 1)
        scan3_kernel<<<nchunks - 1, 1024, 0, stream>>>(csum, rowptr, n);

    int sb = (quarter + n + 255) / 256;
    scatter_kernel<<<sb, 256, 0, stream>>>(ei, E, n, flag, rowptr, deg, col);

    int ab = (n + 3) / 4;

    // layer 1 aggregation (gemm1 already done in fused kernel)
    gat_agg_kernel<<<ab, 256, 0, stream>>>(h16, As, Ad, rowptr, col, b1, hF, n, 1);
    // layer 2
    gemm_h_kernel<<<gb, 256, 0, stream>>>(hF, W2, a2s, a2d, h16, As, Ad, n);
    gat_agg_kernel<<<ab, 256, 0, stream>>>(h16, As, Ad, rowptr, col, b2, hF, n, 0);
    // head
    fc_kernel<<<gb, 256, 0, stream>>>(hF, fcw, fcb, out, n);
}